// Round 11
// baseline (95.302 us; speedup 1.0000x reference)
//
#include <hip/hip_runtime.h>

// CRF loss: A=8, S=200, B=64, T=32. scores (A,S,B,T,T) f32, targets (A,S,B) i32,
// mask (S,B) bool, a_mask (A,B) bool -- bool width (u8 vs i32) runtime-detected.
// Structure = R6 (PASSED, 83.4us): one 8-wave block per chain, wave 0 is
// producer+consumer, __syncthreads per phase, depth-3 producer prefetch,
// runtime consumer j-loop, renorm at s%4==0. Delta vs R6: consumer w-vector is
// broadcast via __shfl from wcur (NO intra-consumer LDS writes at all -- the
// w LDS round-trip, common to all three failing unrolled variants, is gone;
// also shortens the serial chain per step).
constexpr int A_ = 8, S_ = 200, B_ = 64, T_ = 32;
constexpr int START_TAG = 30, END_TAG = 31;
constexpr int NW = 8;                      // waves per block = tiles per phase
#define LOG2E 1.44269504088896340736f
#define LN2   0.69314718055994530942f

#if __has_builtin(__builtin_amdgcn_exp2f)
#define EXP2F(x) __builtin_amdgcn_exp2f(x)
#else
#define EXP2F(x) __expf((x) * LN2)
#endif

__device__ __forceinline__ int load_flag(const void* p, bool u8, int idx) {
    return u8 ? (int)((const unsigned char*)p)[idx] : ((const int*)p)[idx];
}

__global__ __launch_bounds__(NW * 64)
void crf_loss_kernel(const float* __restrict__ scores,
                     const int* __restrict__ targets,
                     const void* __restrict__ mask,
                     const void* __restrict__ amask,
                     float* __restrict__ out)
{
    const int chain = blockIdx.x;          // 0..511
    const int a = chain >> 6;
    const int b = chain & (B_ - 1);
    const int tid = threadIdx.x;
    const int wv = tid >> 6;               // wave 0..7 (wave 0 also consumes)
    const int lane = tid & 63;
    const int t = lane & 31;
    const int fbase = (lane >> 5) << 4;    // 0 or 16

    // bool width detect: mask row 0 is all-true. int view: 1 -> int32, 0x01010101 -> uint8
    const bool bool_u8 = (((const int*)mask)[0] != 1);
    if (!load_flag(amask, bool_u8, a * B_ + b)) return;   // uniform block exit

    __shared__ __align__(16) float ebuf[2][NW][T_ * T_];  // 2 x 8 x 4KB exp-tiles
    __shared__ float gside[2][NW];                        // raw gold-path scores
    __shared__ int tg_lds[S_];

    // ---- first false mask index L (prefix mask) ----
    int L = S_;
    for (int base = 0; base < S_; base += 64) {
        int i = base + lane;
        int mv = (i < S_) ? load_flag(mask, bool_u8, i * B_ + b) : 1;
        unsigned long long bal = __ballot(mv == 0);
        if (bal != 0ull && L == S_) L = base + (int)__builtin_ctzll(bal);
    }

    for (int i = tid; i < S_; i += NW * 64)
        tg_lds[i] = targets[((size_t)a * S_ + i) * B_ + b];
    __syncthreads();                        // tg_lds ready

    const size_t s_stride = (size_t)B_ * T_ * T_;         // 65536 floats per step
    const float* cb = scores + ((size_t)a * S_ * B_ + b) * (T_ * T_);

    // consumer state: wcur = w[t] valid on ALL 64 lanes (both halves load same t)
    float wcur = 0.0f, C2 = 0.0f, tg = 0.0f;
    if (wv == 0) {
        wcur = EXP2F(cb[START_TAG * T_ + t] * LOG2E);
        tg = cb[tg_lds[0]];
    }

    const int nch = (L - 1 + NW - 1) / NW;  // phases (block-uniform)

#define E4(DST, SRC) do {                                                \
        DST.x = EXP2F(SRC.x * LOG2E); DST.y = EXP2F(SRC.y * LOG2E);      \
        DST.z = EXP2F(SRC.z * LOG2E); DST.w = EXP2F(SRC.w * LOG2E);      \
    } while (0)

    // shuffle-only renorm (exact power of 2); wcur valid on all lanes
#define RENORM do {                                                      \
        float m_ = wcur;                                                 \
        m_ = fmaxf(m_, __shfl_xor(m_, 1));                               \
        m_ = fmaxf(m_, __shfl_xor(m_, 2));                               \
        m_ = fmaxf(m_, __shfl_xor(m_, 4));                               \
        m_ = fmaxf(m_, __shfl_xor(m_, 8));                               \
        m_ = fmaxf(m_, __shfl_xor(m_, 16));                              \
        int eb_ = (__float_as_int(m_) >> 23) & 0xff;                     \
        C2 += (float)(eb_ - 127);                                        \
        float sc2_ = __int_as_float((254 - eb_) << 23);                  \
        wcur *= sc2_;                                                    \
    } while (0)

#define TLOAD(Q0, Q1, Q2, Q3, GR, SC) do {                               \
        const int s_ = (SC);                                             \
        if (s_ < L) {                                                    \
            const float*  p_  = cb + (size_t)s_ * s_stride;              \
            const float4* p4_ = (const float4*)p_;                       \
            Q0 = p4_[lane];       Q1 = p4_[64 + lane];                   \
            Q2 = p4_[128 + lane]; Q3 = p4_[192 + lane];                  \
            GR = p_[tg_lds[s_]];                                         \
        }                                                                \
    } while (0)

    // ---- producer prologue prefetch: chunk 0 -> q, chunk 1 -> n ----
    float4 q0, q1, q2, q3, n0, n1, n2, n3, m0, m1, m2, m3;
    float gq = 0.0f, gn = 0.0f, gm = 0.0f;
    TLOAD(q0, q1, q2, q3, gq, 1 + wv);
    TLOAD(n0, n1, n2, n3, gn, 1 + NW + wv);

    for (int k = 0; k < nch; ++k) {
        const int scur = 1 + k * NW + wv;

        // issue chunk k+2 loads (in flight across the barrier & consumer phase)
        TLOAD(m0, m1, m2, m3, gm, scur + 2 * NW);

        // exp-transform chunk k (q regs) into LDS half (k&1)
        if (scur < L) {
            float4* eb = (float4*)&ebuf[k & 1][wv][0];
            float4 e0, e1, e2, e3;
            E4(e0, q0); E4(e1, q1); E4(e2, q2); E4(e3, q3);
            eb[lane] = e0; eb[64 + lane] = e1;
            eb[128 + lane] = e2; eb[192 + lane] = e3;
            if (lane == 0) gside[k & 1][wv] = gq;
        }
        __syncthreads();                    // half (k&1) published

        if (wv == 0) {
            // consumer: runtime j-loop (proven form); w broadcast via shuffles
            const int kb = k & 1;
            const int jmax = min(NW, L - 1 - k * NW);
            for (int j = 0; j < jmax; ++j) {
                const int s = 1 + k * NW + j;
                const float* eb = &ebuf[kb][j][0];
                float e_[16], w_[16];
#pragma unroll
                for (int i = 0; i < 16; ++i)
                    e_[i] = eb[((fbase + i) << 5) | t];
#pragma unroll
                for (int i = 0; i < 16; ++i)
                    w_[i] = __shfl(wcur, fbase + i);   // w[fbase+i] from lane fbase+i
                float s0_ = fmaf(e_[3], w_[3], fmaf(e_[2], w_[2],
                            fmaf(e_[1], w_[1], e_[0] * w_[0])));
                float s1_ = fmaf(e_[7], w_[7], fmaf(e_[6], w_[6],
                            fmaf(e_[5], w_[5], e_[4] * w_[4])));
                float s2_ = fmaf(e_[11], w_[11], fmaf(e_[10], w_[10],
                            fmaf(e_[9], w_[9], e_[8] * w_[8])));
                float s3_ = fmaf(e_[15], w_[15], fmaf(e_[14], w_[14],
                            fmaf(e_[13], w_[13], e_[12] * w_[12])));
                float s_ = (s0_ + s1_) + (s2_ + s3_);
                s_ += __shfl_xor(s_, 32);   // full f-sum on all lanes
                wcur = s_;
                tg += gside[kb][j];
                if ((s & 3) == 0) RENORM;
            }
        }

        // rotate prefetch registers (static names)
        q0 = n0; q1 = n1; q2 = n2; q3 = n3; gq = gn;
        n0 = m0; n1 = m1; n2 = m2; n3 = m3; gn = gm;
    }

    // ---- epilogue (consumer): logZ = ln(w[END_TAG]) + C2*ln2 ----
    if (wv == 0) {
        float wend = __shfl(wcur, END_TAG);
        float logZ = __logf(wend) + C2 * LN2;
        if (lane == 0)
            atomicAdd(out, (logZ - tg) * (1.0f / (float)B_));
    }
}

extern "C" void kernel_launch(void* const* d_in, const int* in_sizes, int n_in,
                              void* d_out, int out_size, void* d_ws, size_t ws_size,
                              hipStream_t stream) {
    const float* scores = (const float*)d_in[0];
    const int* targets  = (const int*)d_in[1];
    const void* mask    = d_in[2];
    const void* amask   = d_in[3];
    float* out = (float*)d_out;

    hipMemsetAsync(out, 0, sizeof(float), stream);
    crf_loss_kernel<<<dim3(A_ * B_), dim3(NW * 64), 0, stream>>>(
        scores, targets, mask, amask, out);
}

// Round 12
// 80.487 us; speedup vs baseline: 1.1841x; 1.1841x over previous
//
#include <hip/hip_runtime.h>

// CRF loss: A=8, S=200, B=64, T=32. scores (A,S,B,T,T) f32, targets (A,S,B) i32,
// mask (S,B) bool, a_mask (A,B) bool -- bool width (u8 vs i32) runtime-detected.
// One 8-wave block per chain; wave 0 = producer+consumer (R6, PASSED 83.4us).
// Consumer body verbatim R6 (LDS wlds, runtime j-loop, renorm s%4==0).
// NEW vs R6: (1) raw lgkm-only barrier (R7-proven) -- no vmcnt(0) drain, global
// loads stay in flight across barriers; (2) k-loop unrolled by 2 with two NAMED
// register buffer sets, TLOAD refills the same regs right after their exp-write
// -- no rotation copies, so first read of a loaded buffer is 2 full phases
// after issue (>= 2x phase length of latency cover, zero-wait counted vmcnt).
constexpr int A_ = 8, S_ = 200, B_ = 64, T_ = 32;
constexpr int START_TAG = 30, END_TAG = 31;
constexpr int NW = 8;                      // waves per block = tiles per phase
#define LOG2E 1.44269504088896340736f
#define LN2   0.69314718055994530942f

#if __has_builtin(__builtin_amdgcn_exp2f)
#define EXP2F(x) __builtin_amdgcn_exp2f(x)
#else
#define EXP2F(x) __expf((x) * LN2)
#endif

__device__ __forceinline__ int load_flag(const void* p, bool u8, int idx) {
    return u8 ? (int)((const unsigned char*)p)[idx] : ((const int*)p)[idx];
}

// LDS-writes-visible barrier WITHOUT vmcnt drain (R7-proven correctness).
#define LGKM_BARRIER do {                                                \
        asm volatile("s_waitcnt lgkmcnt(0)" ::: "memory");               \
        __builtin_amdgcn_s_barrier();                                    \
        asm volatile("" ::: "memory");                                   \
    } while (0)

__global__ __launch_bounds__(NW * 64)
void crf_loss_kernel(const float* __restrict__ scores,
                     const int* __restrict__ targets,
                     const void* __restrict__ mask,
                     const void* __restrict__ amask,
                     float* __restrict__ out)
{
    const int chain = blockIdx.x;          // 0..511
    const int a = chain >> 6;
    const int b = chain & (B_ - 1);
    const int tid = threadIdx.x;
    const int wv = tid >> 6;               // wave 0..7 (wave 0 also consumes)
    const int lane = tid & 63;
    const int t = lane & 31;
    const int fbase = (lane >> 5) << 4;    // 0 or 16

    // bool width detect: mask row 0 is all-true. int view: 1 -> int32, 0x01010101 -> uint8
    const bool bool_u8 = (((const int*)mask)[0] != 1);
    if (!load_flag(amask, bool_u8, a * B_ + b)) return;   // uniform block exit

    __shared__ __align__(16) float ebuf[2][NW][T_ * T_];  // 2 x 8 x 4KB exp-tiles
    __shared__ float gside[2][NW];                        // raw gold-path scores
    __shared__ int tg_lds[S_];
    __shared__ float wlds[T_];                            // w vector (wave 0 only)

    // ---- first false mask index L (prefix mask) ----
    int L = S_;
    for (int base = 0; base < S_; base += 64) {
        int i = base + lane;
        int mv = (i < S_) ? load_flag(mask, bool_u8, i * B_ + b) : 1;
        unsigned long long bal = __ballot(mv == 0);
        if (bal != 0ull && L == S_) L = base + (int)__builtin_ctzll(bal);
    }

    for (int i = tid; i < S_; i += NW * 64)
        tg_lds[i] = targets[((size_t)a * S_ + i) * B_ + b];
    __syncthreads();                        // tg_lds ready (drain fine in prologue)

    const size_t s_stride = (size_t)B_ * T_ * T_;         // 65536 floats per step
    const float* cb = scores + ((size_t)a * S_ * B_ + b) * (T_ * T_);

    float wcur = 0.0f, C2 = 0.0f, tg = 0.0f;
    if (wv == 0) {                          // consumer init
        wcur = EXP2F(cb[START_TAG * T_ + t] * LOG2E);
        if (lane < 32) wlds[lane] = wcur;
        tg = cb[tg_lds[0]];
    }

    const int nch = (L - 1 + NW - 1) / NW;  // phases (block-uniform)

#define E4(DST, SRC) do {                                                \
        DST.x = EXP2F(SRC.x * LOG2E); DST.y = EXP2F(SRC.y * LOG2E);      \
        DST.z = EXP2F(SRC.z * LOG2E); DST.w = EXP2F(SRC.w * LOG2E);      \
    } while (0)

#define RENORM do {                                                      \
        float m_ = wcur;                                                 \
        m_ = fmaxf(m_, __shfl_xor(m_, 1));                               \
        m_ = fmaxf(m_, __shfl_xor(m_, 2));                               \
        m_ = fmaxf(m_, __shfl_xor(m_, 4));                               \
        m_ = fmaxf(m_, __shfl_xor(m_, 8));                               \
        m_ = fmaxf(m_, __shfl_xor(m_, 16));                              \
        int eb_ = (__float_as_int(m_) >> 23) & 0xff;                     \
        C2 += (float)(eb_ - 127);                                        \
        float sc2_ = __int_as_float((254 - eb_) << 23);                  \
        wcur *= sc2_;                                                    \
        if (lane < 32) wlds[lane] = wcur;                                \
    } while (0)

#define TLOAD(Q0, Q1, Q2, Q3, GR, SC) do {                               \
        const int s_ = (SC);                                             \
        if (s_ < L) {                                                    \
            const float*  p_  = cb + (size_t)s_ * s_stride;              \
            const float4* p4_ = (const float4*)p_;                       \
            Q0 = p4_[lane];       Q1 = p4_[64 + lane];                   \
            Q2 = p4_[128 + lane]; Q3 = p4_[192 + lane];                  \
            GR = p_[tg_lds[s_]];                                         \
        }                                                                \
    } while (0)

    // consumer phase: verbatim R6 body (runtime j-loop, LDS wlds, renorm s%4==0)
#define CONSUME(KK) do {                                                 \
        const int kb_ = (KK) & 1;                                        \
        const int jmax_ = min(NW, L - 1 - (KK) * NW);                    \
        for (int j = 0; j < jmax_; ++j) {                                \
            const int s = 1 + (KK) * NW + j;                             \
            const float* eb = &ebuf[kb_][j][0];                          \
            float4 wa_ = *(const float4*)&wlds[fbase];                   \
            float4 wb_ = *(const float4*)&wlds[fbase + 4];               \
            float4 wc_ = *(const float4*)&wlds[fbase + 8];               \
            float4 wd_ = *(const float4*)&wlds[fbase + 12];              \
            float e_[16];                                                \
            _Pragma("unroll")                                            \
            for (int i = 0; i < 16; ++i)                                 \
                e_[i] = eb[((fbase + i) << 5) | t];                      \
            float s0_ = fmaf(e_[3], wa_.w, fmaf(e_[2], wa_.z,            \
                        fmaf(e_[1], wa_.y, e_[0] * wa_.x)));             \
            float s1_ = fmaf(e_[7], wb_.w, fmaf(e_[6], wb_.z,            \
                        fmaf(e_[5], wb_.y, e_[4] * wb_.x)));             \
            float s2_ = fmaf(e_[11], wc_.w, fmaf(e_[10], wc_.z,          \
                        fmaf(e_[9], wc_.y, e_[8] * wc_.x)));             \
            float s3_ = fmaf(e_[15], wd_.w, fmaf(e_[14], wd_.z,          \
                        fmaf(e_[13], wd_.y, e_[12] * wd_.x)));           \
            float s_ = (s0_ + s1_) + (s2_ + s3_);                        \
            s_ += __shfl_xor(s_, 32);                                    \
            wcur = s_;                                                   \
            if (lane < 32) wlds[lane] = s_;                              \
            tg += gside[kb_][j];                                         \
            if ((s & 3) == 0) RENORM;                                    \
        }                                                                \
    } while (0)

    // One phase with buffer set (Q0..Q3,GQ): exp-write chunk KK, refill the
    // SAME regs with chunk KK+2 (first read is 2 phases later), raw barrier,
    // wave-0 consume. No register rotation anywhere.
#define PHASE(Q0, Q1, Q2, Q3, GQ, KK) do {                               \
        const int k_ = (KK);                                             \
        const int scur_ = 1 + k_ * NW + wv;                              \
        if (scur_ < L) {                                                 \
            float4* ebw = (float4*)&ebuf[k_ & 1][wv][0];                 \
            float4 e0, e1, e2, e3;                                       \
            E4(e0, Q0); E4(e1, Q1); E4(e2, Q2); E4(e3, Q3);              \
            ebw[lane] = e0; ebw[64 + lane] = e1;                         \
            ebw[128 + lane] = e2; ebw[192 + lane] = e3;                  \
            if (lane == 0) gside[k_ & 1][wv] = GQ;                       \
        }                                                                \
        TLOAD(Q0, Q1, Q2, Q3, GQ, scur_ + 2 * NW);                       \
        LGKM_BARRIER;                                                    \
        if (wv == 0) CONSUME(k_);                                        \
    } while (0)

    // ---- prologue prefetch: chunk 0 -> A, chunk 1 -> B ----
    float4 a0, a1, a2, a3, b0, b1, b2, b3;
    float ga = 0.0f, gb = 0.0f;
    TLOAD(a0, a1, a2, a3, ga, 1 + wv);
    TLOAD(b0, b1, b2, b3, gb, 1 + NW + wv);

    for (int k = 0; k < nch; k += 2) {
        PHASE(a0, a1, a2, a3, ga, k);
        if (k + 1 < nch)
            PHASE(b0, b1, b2, b3, gb, k + 1);
    }

    // ---- epilogue (consumer): logZ = ln(w[END_TAG]) + C2*ln2 ----
    if (wv == 0) {
        float wend = __shfl(wcur, END_TAG);
        float logZ = __logf(wend) + C2 * LN2;
        if (lane == 0)
            atomicAdd(out, (logZ - tg) * (1.0f / (float)B_));
    }
}

extern "C" void kernel_launch(void* const* d_in, const int* in_sizes, int n_in,
                              void* d_out, int out_size, void* d_ws, size_t ws_size,
                              hipStream_t stream) {
    const float* scores = (const float*)d_in[0];
    const int* targets  = (const int*)d_in[1];
    const void* mask    = d_in[2];
    const void* amask   = d_in[3];
    float* out = (float*)d_out;

    hipMemsetAsync(out, 0, sizeof(float), stream);
    crf_loss_kernel<<<dim3(A_ * B_), dim3(NW * 64), 0, stream>>>(
        scores, targets, mask, amask, out);
}